// Round 5
// baseline (1079.553 us; speedup 1.0000x reference)
//
#include <hip/hip_runtime.h>
#include <stdint.h>

#define N_NODES 100000
#define D_IN 512
#define D_H 128
#define N_EDGES 1600000

// ---------------- threefry2x32 (JAX-compatible, 20 rounds) ----------------
__host__ __device__ __forceinline__ void threefry2x32(uint32_t k0, uint32_t k1,
                                                      uint32_t x0, uint32_t x1,
                                                      uint32_t& o0, uint32_t& o1) {
  uint32_t k2 = k0 ^ k1 ^ 0x1BD11BDAu;
  x0 += k0; x1 += k1;
#if defined(__HIP_DEVICE_COMPILE__)
#define ROTL(v, r) __builtin_rotateleft32((v), (r))
#else
#define ROTL(v, r) (((v) << (r)) | ((v) >> (32 - (r))))
#endif
#define TFR(r) x0 += x1; x1 = ROTL(x1, r); x1 ^= x0;
  TFR(13) TFR(15) TFR(26) TFR(6)
  x0 += k1; x1 += k2 + 1u;
  TFR(17) TFR(29) TFR(16) TFR(24)
  x0 += k2; x1 += k0 + 2u;
  TFR(13) TFR(15) TFR(26) TFR(6)
  x0 += k0; x1 += k1 + 3u;
  TFR(17) TFR(29) TFR(16) TFR(24)
  x0 += k1; x1 += k2 + 4u;
  TFR(13) TFR(15) TFR(26) TFR(6)
  x0 += k2; x1 += k0 + 5u;
#undef TFR
#undef ROTL
  o0 = x0; o1 = x1;
}

// partitionable random_bits for index i (< 2^32): xor of the two output lanes
__device__ __forceinline__ uint32_t tf_bits(uint32_t k0, uint32_t k1, uint32_t i) {
  uint32_t w0, w1;
  threefry2x32(k0, k1, 0u, i, w0, w1);
  return w0 ^ w1;
}

__device__ __forceinline__ float bits_to_unit(uint32_t b) {
  return __uint_as_float((b >> 9) | 0x3f800000u) - 1.0f;
}

__device__ __forceinline__ unsigned short f2bf(float f) {  // RNE, finite only
  uint32_t b = __float_as_uint(f);
  return (unsigned short)((b + 0x7FFFu + ((b >> 16) & 1u)) >> 16);
}

// Giles (2012) single-precision erfinv: ~1e-6 rel err, branch-free select.
__device__ __forceinline__ float erfinv_fast(float x) {
  float w = -__logf(fmaf(-x, x, 1.0f));
  float wc = w - 2.5f;
  float p = 2.81022636e-08f;
  p = fmaf(p, wc, 3.43273939e-07f);
  p = fmaf(p, wc, -3.5233877e-06f);
  p = fmaf(p, wc, -4.39150654e-06f);
  p = fmaf(p, wc, 0.00021858087f);
  p = fmaf(p, wc, -0.00125372503f);
  p = fmaf(p, wc, -0.00417768164f);
  p = fmaf(p, wc, 0.246640727f);
  p = fmaf(p, wc, 1.50140941f);
  // sqrt(w) = w * rsqrt(w); w==0 -> NaN but then w<5 selects p-branch.
  float wt = fmaf(w, rsqrtf(w), -3.0f);
  float q = -0.000200214257f;
  q = fmaf(q, wt, 0.000100950558f);
  q = fmaf(q, wt, 0.00134934322f);
  q = fmaf(q, wt, -0.00367342844f);
  q = fmaf(q, wt, 0.00573950773f);
  q = fmaf(q, wt, -0.0076224613f);
  q = fmaf(q, wt, 0.00943887047f);
  q = fmaf(q, wt, 1.00167406f);
  q = fmaf(q, wt, 2.83297682f);
  return ((w < 5.0f) ? p : q) * x;
}

#define PE 0.60000002384185791f   // (float)(1.0 - 0.4)

// ---------------- prep: detect + zero counts/stats/bar + Wt transpose ----------
__global__ __launch_bounds__(256) void prep_kernel(
    const int* __restrict__ adj32, int* __restrict__ flag,
    int* __restrict__ counts, float* __restrict__ stats,
    const float* __restrict__ W, unsigned short* __restrict__ Wt,
    int* __restrict__ bar) {
  int idx = blockIdx.x * 256 + threadIdx.x;
  if (blockIdx.x == 0 && threadIdx.x < 64) {
    bool hi_zero = (adj32[2 * threadIdx.x + 1] == 0);
    unsigned long long bl = __ballot(hi_zero);
    if (threadIdx.x == 0) *flag = (bl == ~0ull) ? 1 : 0;
  }
  if (idx == 0) *bar = 0;
  if (idx < N_NODES) counts[idx] = 0;
  if (idx < 256) stats[idx] = 0.0f;
  if (idx < D_IN * D_H) {  // W (f32 [512][128]) -> Wt (bf16 [128][512])
    int k = idx >> 7, n = idx & 127;
    Wt[n * 512 + k] = f2bf(W[idx]);
  }
}

// ---------------- fused: gen_x with sparsity compaction (4/5) + edge-hist (1/5) ----
// Direct block mapping (r3 version: VGPR 12, ~79% occupancy).
#define GEN_BLKS 25000
#define EDGE_BLKS 6250
#define MAIN_BLKS 31250

__global__ __launch_bounds__(256) void fused_kernel(
    const float* __restrict__ data, unsigned short* __restrict__ x,
    const int* __restrict__ adj32, const int* __restrict__ flag,
    int* __restrict__ counts,
    uint32_t kn0, uint32_t kn1, uint32_t kd10, uint32_t kd11,
    uint32_t kd20, uint32_t kd21, uint32_t ke0, uint32_t ke1) {
  __shared__ uint2 queue[4][512];            // 16 KiB: {d_bits, local_idx}
  __shared__ unsigned short res[4][512];     //  4 KiB: bf16 results
  int b = blockIdx.x;
  if ((b % 5) == 4) {
    // ---- edge-hist block ----
    uint32_t e = (uint32_t)(b / 5) * 256u + threadIdx.x;  // < 1.6M exactly
    int fl = *flag;
    int r = fl ? adj32[2 * e] : adj32[e];
    uint32_t eb = tf_bits(ke0, ke1, e);
    if (bits_to_unit(eb) < PE) atomicAdd(&counts[r], 1);
    return;
  }
  // ---- gen block: 2048 elements; each wave owns a 512-element chunk ----
  uint32_t gblk = (uint32_t)(b / 5) * 4u + (uint32_t)(b % 5);
  const int wave = threadIdx.x >> 6, lane = threadIdx.x & 63;
  const uint32_t wbase = gblk * 2048u + (uint32_t)wave * 512u;
  const uint32_t i0 = wbase + (uint32_t)lane * 8u;
  float4 d0 = *(const float4*)(data + i0);
  float4 d1 = *(const float4*)(data + i0 + 4);
  float dv[8] = {d0.x, d0.y, d0.z, d0.w, d1.x, d1.y, d1.z, d1.w};
  // zero result tile (survivors overwrite in phase 2); dropped -> bf16 +0
  *(uint4*)(&res[wave][lane * 8]) = make_uint4(0u, 0u, 0u, 0u);

  // phase 1: mask-1 threefry for all elements; push survivors (~50%)
  uint32_t qc = 0;
#pragma unroll
  for (int j = 0; j < 8; ++j) {
    uint32_t ab = tf_bits(kd10, kd11, i0 + (uint32_t)j);
    bool keep = (ab >> 31) == 0u;
    unsigned long long m = __ballot(keep);
    uint32_t below = __builtin_amdgcn_mbcnt_hi(
        (uint32_t)(m >> 32), __builtin_amdgcn_mbcnt_lo((uint32_t)m, 0u));
    if (keep)
      queue[wave][qc + below] =
          make_uint2(__float_as_uint(dv[j]), (uint32_t)(lane * 8 + j));
    qc += (uint32_t)__popcll(m);
  }

  // phase 1b: mask-2 threefry on queued entries; compact in place (~25% remain).
  uint32_t qc2 = 0;
  for (uint32_t k0 = 0; k0 < qc; k0 += 64) {
    uint32_t k = k0 + (uint32_t)lane;
    bool act = k < qc;
    uint2 ent = make_uint2(0u, 0u);
    if (act) ent = queue[wave][k];
    uint32_t bb = tf_bits(kd20, kd21, wbase + ent.y);
    bool keep = act && ((bb >> 31) == 0u);
    unsigned long long m = __ballot(keep);
    uint32_t below = __builtin_amdgcn_mbcnt_hi(
        (uint32_t)(m >> 32), __builtin_amdgcn_mbcnt_lo((uint32_t)m, 0u));
    if (keep) queue[wave][qc2 + below] = ent;
    qc2 += (uint32_t)__popcll(m);
  }

  // phase 2: noise threefry + erfinv only for final survivors
  for (uint32_t k0 = 0; k0 < qc2; k0 += 64) {
    uint32_t k = k0 + (uint32_t)lane;
    bool act = k < qc2;
    uint2 ent = make_uint2(0u, 0u);
    if (act) ent = queue[wave][k];
    uint32_t nb = tf_bits(kn0, kn1, wbase + ent.y);
    float f = bits_to_unit(nb);
    float u = fmaf(f, 2.0f, -0.99999994f);  // >= -0.99999994 always
    float z = erfinv_fast(u);
    float val = fmaf(0.0141421356237f, z, __uint_as_float(ent.x));
    unsigned short r = f2bf(val * 4.0f);
    if (act) res[wave][ent.y] = r;
  }

  // phase 3: coalesced 16 B store per lane
  uint4 rr = *(const uint4*)(&res[wave][lane * 8]);
  *(uint4*)(x + i0) = rr;
}

// ---------------- gemm: h = x @ W (bf16 MFMA, f32 acc, fp16 h out) ----------------
typedef __attribute__((ext_vector_type(8))) short bf16x8;
typedef __attribute__((ext_vector_type(4))) float f32x4;
typedef _Float16 half8 __attribute__((ext_vector_type(8)));
#define BM 64
#define BK 64
#define LDT 72  // padded LDS leading dim (elements)

__global__ __launch_bounds__(256) void gemm_kernel(
    const unsigned short* __restrict__ x, const unsigned short* __restrict__ Wt,
    unsigned short* __restrict__ hh) {
  __shared__ __align__(16) unsigned short a_lds[BM * LDT];
  __shared__ __align__(16) unsigned short b_lds[128 * LDT];
  const int tid = threadIdx.x;
  const int r0 = blockIdx.x * BM;
  const int wave = tid >> 6, lane = tid & 63;
  const int lane15 = lane & 15, quad = lane >> 4;
  const int waveM = (wave & 1) * 32, waveN = (wave >> 1) * 64;
  f32x4 acc[2][4] = {};
  for (int kc = 0; kc < D_IN; kc += BK) {
    __syncthreads();
    {
      int row = tid >> 2, q = tid & 3;
      int gr = r0 + row;
      uint4 v0 = make_uint4(0, 0, 0, 0), v1 = v0;
      if (gr < N_NODES) {
        const unsigned short* src = x + (size_t)gr * D_IN + kc + q * 16;
        v0 = *(const uint4*)(src);
        v1 = *(const uint4*)(src + 8);
      }
      *(uint4*)(a_lds + row * LDT + q * 16) = v0;
      *(uint4*)(a_lds + row * LDT + q * 16 + 8) = v1;
    }
    {
      int n = tid >> 1, half = tid & 1;
      const uint4* src = (const uint4*)(Wt + n * 512 + kc + half * 32);
      uint4* dst = (uint4*)(b_lds + n * LDT + half * 32);
      dst[0] = src[0]; dst[1] = src[1]; dst[2] = src[2]; dst[3] = src[3];
    }
    __syncthreads();
    for (int ks = 0; ks < BK; ks += 32) {
      bf16x8 afrag[2], bfrag[4];
      for (int m = 0; m < 2; ++m)
        afrag[m] = *(const bf16x8*)(a_lds + (waveM + m * 16 + lane15) * LDT + ks + quad * 8);
      for (int n = 0; n < 4; ++n)
        bfrag[n] = *(const bf16x8*)(b_lds + (waveN + n * 16 + lane15) * LDT + ks + quad * 8);
      for (int m = 0; m < 2; ++m)
        for (int n = 0; n < 4; ++n)
          acc[m][n] = __builtin_amdgcn_mfma_f32_16x16x32_bf16(afrag[m], bfrag[n], acc[m][n], 0, 0, 0);
    }
  }
  for (int m = 0; m < 2; ++m) {
    int growb = r0 + waveM + m * 16 + quad * 4;
    for (int r = 0; r < 4; ++r) {
      int grow = growb + r;
      if (grow < N_NODES)
        for (int n = 0; n < 4; ++n) {
          _Float16 hv = (_Float16)acc[m][n][r];
          hh[(size_t)grow * D_H + waveN + n * 16 + lane15] =
              __builtin_bit_cast(unsigned short, hv);
        }
    }
  }
}

// ---------------- post: scan1 -> scan23 -> scatter -> spmm+stats -> bn ---------
// ONE kernel with manual grid barriers. Grid MUST be <= 4 blocks/CU * 256 CU
// (co-residency guaranteed by __launch_bounds__(256,4): 4 waves/EU).
#define SCAN_B 512
#define SCAN_NBLK ((N_NODES + SCAN_B - 1) / SCAN_B)  // 196
#define POST_BLKS 1024

__device__ __forceinline__ void grid_barrier(int* bar, int target) {
  __syncthreads();
  if (threadIdx.x == 0) {
    __threadfence();  // flush prior global writes device-wide
    __hip_atomic_fetch_add(bar, 1, __ATOMIC_ACQ_REL, __HIP_MEMORY_SCOPE_AGENT);
    while (__hip_atomic_load(bar, __ATOMIC_ACQUIRE, __HIP_MEMORY_SCOPE_AGENT) <
           target)
      __builtin_amdgcn_s_sleep(2);
  }
  __syncthreads();
}

__global__ __launch_bounds__(256, 4) void post_kernel(
    int* __restrict__ counts, int* __restrict__ rowstart,
    int* __restrict__ bsums, int* __restrict__ cursor,
    const int* __restrict__ adj32, const int* __restrict__ flag,
    const float* __restrict__ vals, int* __restrict__ scol,
    float* __restrict__ sval, const unsigned short* __restrict__ hh,
    float* __restrict__ agg, float* __restrict__ stats,
    const float* __restrict__ gamma, const float* __restrict__ beta,
    float* __restrict__ out, int* __restrict__ bar,
    uint32_t ke0, uint32_t ke1) {
  __shared__ int bufA[SCAN_B], bufB[SCAN_B];
  __shared__ int bscan_l[256];
  __shared__ float ls[4][128], lq[4][128];
  const int t = threadIdx.x;

  // ---- P0: scan1 (per-512-chunk exclusive scan of counts) ----
  for (int sb = blockIdx.x; sb < SCAN_NBLK; sb += gridDim.x) {
    int g0 = sb * SCAN_B + t, g1 = g0 + 256;
    int v0 = (g0 < N_NODES) ? counts[g0] : 0;
    int v1 = (g1 < N_NODES) ? counts[g1] : 0;
    bufA[t] = v0; bufA[t + 256] = v1;
    __syncthreads();
    int* src = bufA; int* dst = bufB;
    for (int off = 1; off < SCAN_B; off <<= 1) {
      for (int k = t; k < SCAN_B; k += 256)
        dst[k] = src[k] + ((k >= off) ? src[k - off] : 0);
      __syncthreads();
      int* tmp = src; src = dst; dst = tmp;
    }
    if (g0 < N_NODES) rowstart[g0] = src[t] - v0;
    if (g1 < N_NODES) rowstart[g1] = src[t + 256] - v1;
    if (t == 0) bsums[sb] = src[SCAN_B - 1];
    __syncthreads();
  }
  grid_barrier(bar, gridDim.x * 1);

  // ---- P1: scan23 (scan block sums redundantly per block, apply) ----
  {
    int v = (t < SCAN_NBLK) ? bsums[t] : 0;
    bufA[t] = v;
    __syncthreads();
    int* src = bufA; int* dst = bufB;
    for (int off = 1; off < 256; off <<= 1) {
      dst[t] = src[t] + ((t >= off) ? src[t - off] : 0);
      __syncthreads();
      int* tmp = src; src = dst; dst = tmp;
    }
    bscan_l[t] = src[t] - v;  // exclusive
    __syncthreads();
    for (int i = blockIdx.x * 256 + t; i < N_NODES; i += gridDim.x * 256) {
      int val = rowstart[i] + bscan_l[i / SCAN_B];
      rowstart[i] = val;
      cursor[i] = val;
    }
  }
  grid_barrier(bar, gridDim.x * 2);

  // ---- P2: scatter kept edges into CSR (recomputes edge dropout) ----
  {
    int fl = *flag;
    uint32_t stride = gridDim.x * 256u;
    for (uint32_t e = blockIdx.x * 256u + t; e < (uint32_t)N_EDGES; e += stride) {
      uint32_t eb = tf_bits(ke0, ke1, e);
      if (bits_to_unit(eb) >= PE) continue;
      int r = fl ? adj32[2 * e] : adj32[e];
      int c = fl ? adj32[2 * (N_EDGES + e)] : adj32[N_EDGES + e];
      int pos = atomicAdd(&cursor[r], 1);
      scol[pos] = c;
      sval[pos] = vals[e] / PE;
    }
  }
  grid_barrier(bar, gridDim.x * 3);

  // ---- P3: CSR SpMM + ELU + BN-stats (wave/row; 4 edges via 16-lane groups) ----
  {
    const int wave = t >> 6, lane = t & 63;
    const int g = lane >> 4, l4 = lane & 15;
    const unsigned short* hp = hh + l4 * 8;
    float es[8] = {}, eq[8] = {};
    const int wstride = gridDim.x * 4;
    for (int r = blockIdx.x * 4 + wave; r < N_NODES; r += wstride) {
      int start = rowstart[r], len = counts[r];
      float acc[8] = {};
      int j = 0;
      for (; j + 8 <= len; j += 8) {
        int e0 = start + j + g, e1 = e0 + 4;
        int c0 = scol[e0], c1 = scol[e1];
        float v0 = sval[e0], v1 = sval[e1];
        uint4 b0 = *(const uint4*)(hp + (size_t)c0 * D_H);
        uint4 b1 = *(const uint4*)(hp + (size_t)c1 * D_H);
        half8 x0 = __builtin_bit_cast(half8, b0);
        half8 x1 = __builtin_bit_cast(half8, b1);
#pragma unroll
        for (int k = 0; k < 8; ++k) {
          acc[k] = fmaf(v0, (float)x0[k], acc[k]);
          acc[k] = fmaf(v1, (float)x1[k], acc[k]);
        }
      }
      if (j + g < len) {
        int e = start + j + g;
        int c = scol[e];
        float v = sval[e];
        uint4 bb = *(const uint4*)(hp + (size_t)c * D_H);
        half8 xv = __builtin_bit_cast(half8, bb);
#pragma unroll
        for (int k = 0; k < 8; ++k) acc[k] = fmaf(v, (float)xv[k], acc[k]);
      }
      if (j + 4 + g < len) {
        int e = start + j + 4 + g;
        int c = scol[e];
        float v = sval[e];
        uint4 bb = *(const uint4*)(hp + (size_t)c * D_H);
        half8 xv = __builtin_bit_cast(half8, bb);
#pragma unroll
        for (int k = 0; k < 8; ++k) acc[k] = fmaf(v, (float)xv[k], acc[k]);
      }
#pragma unroll
      for (int k = 0; k < 8; ++k) {
        acc[k] += __shfl_xor(acc[k], 16, 64);
        acc[k] += __shfl_xor(acc[k], 32, 64);
      }
      if (g == 0) {
        float e8[8];
#pragma unroll
        for (int k = 0; k < 8; ++k) {
          float a = acc[k];
          float e = a > 0.f ? a : expm1f(a);
          e8[k] = e;
          es[k] += e;
          eq[k] += e * e;
        }
        float* op = agg + (size_t)r * D_H + l4 * 8;
        *(float4*)op = make_float4(e8[0], e8[1], e8[2], e8[3]);
        *(float4*)(op + 4) = make_float4(e8[4], e8[5], e8[6], e8[7]);
      }
    }
    __syncthreads();  // ls/lq reuse after earlier phases
    if (g == 0) {
#pragma unroll
      for (int k = 0; k < 8; ++k) {
        ls[wave][l4 * 8 + k] = es[k];
        lq[wave][l4 * 8 + k] = eq[k];
      }
    }
    __syncthreads();
    if (t < 128) {
      float s = ls[0][t] + ls[1][t] + ls[2][t] + ls[3][t];
      float q = lq[0][t] + lq[1][t] + lq[2][t] + lq[3][t];
      atomicAdd(&stats[t], s);
      atomicAdd(&stats[128 + t], q);
    }
  }
  grid_barrier(bar, gridDim.x * 4);

  // ---- P4: BN apply (agg already holds ELU output) ----
  {
    const float inv_n = 1.0f / (float)N_NODES;
    const int tot4 = N_NODES * D_H / 4;  // 3,200,000
    int idx0 = blockIdx.x * 256 + t;
    int stride = gridDim.x * 256;  // multiple of 32 -> f0 invariant
    int f0 = (idx0 * 4) & 127;
    float sc[4], sh[4];
#pragma unroll
    for (int j = 0; j < 4; ++j) {
      int f = f0 + j;
      float mean = stats[f] * inv_n;
      float var = stats[128 + f] * inv_n - mean * mean;
      float gsc = gamma[f] * rsqrtf(var + 1e-5f);
      sc[j] = gsc;
      sh[j] = beta[f] - mean * gsc;
    }
    for (int idx4 = idx0; idx4 < tot4; idx4 += stride) {
      size_t base = (size_t)idx4 * 4;
      float4 a = *(const float4*)(agg + base);
      float4 o;
      o.x = fmaf(a.x, sc[0], sh[0]);
      o.y = fmaf(a.y, sc[1], sh[1]);
      o.z = fmaf(a.z, sc[2], sh[2]);
      o.w = fmaf(a.w, sc[3], sh[3]);
      *(float4*)(out + base) = o;
    }
  }
}

// ---------------- launcher ----------------
extern "C" void kernel_launch(void* const* d_in, const int* in_sizes, int n_in,
                              void* d_out, int out_size, void* d_ws, size_t ws_size,
                              hipStream_t stream) {
  const float* data = (const float*)d_in[0];
  const int* adj = (const int*)d_in[1];
  const float* vals = (const float*)d_in[2];
  const float* W = (const float*)d_in[3];
  const float* gamma = (const float*)d_in[4];
  const float* beta = (const float*)d_in[5];
  float* out = (float*)d_out;

  // workspace layout:
  //   [0, 102.4M)      x (bf16)            -- dead after gemm
  //   alias zone (written only after gemm):
  //     [0, 51.2M)     agg
  //     [51.2M, 57.6M) scol
  //     [57.6M, 64.0M) sval
  //     [64.0M, 64.4M) rowstart
  //     [64.4M, 64.8M) cursor
  //     [64.8M, ...)   bsums
  //   [102.4M, 128.0M) h (fp16)
  //   153,600,000      Wt (128K)
  //   153,731,072      stats (1K)
  //   153,732,096      flag (4B)
  //   153,732,100      bar (4B)
  //   153,733,120      counts (400K)       -- outside x: live during fused
  char* ws = (char*)d_ws;
  unsigned short* x = (unsigned short*)ws;
  float* agg = (float*)ws;
  int* scol = (int*)(ws + 51200000);
  float* sval = (float*)(ws + 57600000);
  int* rowstart = (int*)(ws + 64000000);
  int* cursor = (int*)(ws + 64400000);
  int* bsums = (int*)(ws + 64800000);
  unsigned short* hh = (unsigned short*)(ws + 102400000);
  unsigned short* Wt = (unsigned short*)(ws + 153600000);
  float* stats = (float*)(ws + 153731072);
  int* flag = (int*)(ws + 153732096);
  int* bar = (int*)(ws + 153732100);
  int* counts = (int*)(ws + 153733120);

  // host-side: split(key(42), 4) foldlike -> key_i = both words of tf(key,(0,i))
  uint32_t kk[4][2];
  for (uint32_t i = 0; i < 4; ++i) threefry2x32(0u, 42u, 0u, i, kk[i][0], kk[i][1]);
  uint32_t kn0 = kk[0][0], kn1 = kk[0][1];
  uint32_t kd10 = kk[1][0], kd11 = kk[1][1];
  uint32_t kd20 = kk[2][0], kd21 = kk[2][1];
  uint32_t ke0 = kk[3][0], ke1 = kk[3][1];

  prep_kernel<<<391, 256, 0, stream>>>(adj, flag, counts, stats, W, Wt, bar);
  fused_kernel<<<MAIN_BLKS, 256, 0, stream>>>(
      data, x, adj, flag, counts,
      kn0, kn1, kd10, kd11, kd20, kd21, ke0, ke1);
  gemm_kernel<<<(N_NODES + BM - 1) / BM, 256, 0, stream>>>(x, Wt, hh);
  // ---- x dead below; alias zone live ----
  post_kernel<<<POST_BLKS, 256, 0, stream>>>(
      counts, rowstart, bsums, cursor, adj, flag, vals, scol, sval, hh,
      agg, stats, gamma, beta, out, bar, ke0, ke1);
}

// Round 6
// 700.034 us; speedup vs baseline: 1.5421x; 1.5421x over previous
//
#include <hip/hip_runtime.h>
#include <stdint.h>

#define N_NODES 100000
#define D_IN 512
#define D_H 128
#define N_EDGES 1600000

// ---------------- threefry2x32 (JAX-compatible, 20 rounds) ----------------
__host__ __device__ __forceinline__ void threefry2x32(uint32_t k0, uint32_t k1,
                                                      uint32_t x0, uint32_t x1,
                                                      uint32_t& o0, uint32_t& o1) {
  uint32_t k2 = k0 ^ k1 ^ 0x1BD11BDAu;
  x0 += k0; x1 += k1;
#if defined(__HIP_DEVICE_COMPILE__)
#define ROTL(v, r) __builtin_rotateleft32((v), (r))
#else
#define ROTL(v, r) (((v) << (r)) | ((v) >> (32 - (r))))
#endif
#define TFR(r) x0 += x1; x1 = ROTL(x1, r); x1 ^= x0;
  TFR(13) TFR(15) TFR(26) TFR(6)
  x0 += k1; x1 += k2 + 1u;
  TFR(17) TFR(29) TFR(16) TFR(24)
  x0 += k2; x1 += k0 + 2u;
  TFR(13) TFR(15) TFR(26) TFR(6)
  x0 += k0; x1 += k1 + 3u;
  TFR(17) TFR(29) TFR(16) TFR(24)
  x0 += k1; x1 += k2 + 4u;
  TFR(13) TFR(15) TFR(26) TFR(6)
  x0 += k2; x1 += k0 + 5u;
#undef TFR
#undef ROTL
  o0 = x0; o1 = x1;
}

// partitionable random_bits for index i (< 2^32): xor of the two output lanes
__device__ __forceinline__ uint32_t tf_bits(uint32_t k0, uint32_t k1, uint32_t i) {
  uint32_t w0, w1;
  threefry2x32(k0, k1, 0u, i, w0, w1);
  return w0 ^ w1;
}

__device__ __forceinline__ float bits_to_unit(uint32_t b) {
  return __uint_as_float((b >> 9) | 0x3f800000u) - 1.0f;
}

__device__ __forceinline__ unsigned short f2bf(float f) {  // RNE, finite only
  uint32_t b = __float_as_uint(f);
  return (unsigned short)((b + 0x7FFFu + ((b >> 16) & 1u)) >> 16);
}

// Giles (2012) single-precision erfinv: ~1e-6 rel err, branch-free select.
__device__ __forceinline__ float erfinv_fast(float x) {
  float w = -__logf(fmaf(-x, x, 1.0f));
  float wc = w - 2.5f;
  float p = 2.81022636e-08f;
  p = fmaf(p, wc, 3.43273939e-07f);
  p = fmaf(p, wc, -3.5233877e-06f);
  p = fmaf(p, wc, -4.39150654e-06f);
  p = fmaf(p, wc, 0.00021858087f);
  p = fmaf(p, wc, -0.00125372503f);
  p = fmaf(p, wc, -0.00417768164f);
  p = fmaf(p, wc, 0.246640727f);
  p = fmaf(p, wc, 1.50140941f);
  // sqrt(w) = w * rsqrt(w); w==0 -> NaN but then w<5 selects p-branch.
  float wt = fmaf(w, rsqrtf(w), -3.0f);
  float q = -0.000200214257f;
  q = fmaf(q, wt, 0.000100950558f);
  q = fmaf(q, wt, 0.00134934322f);
  q = fmaf(q, wt, -0.00367342844f);
  q = fmaf(q, wt, 0.00573950773f);
  q = fmaf(q, wt, -0.0076224613f);
  q = fmaf(q, wt, 0.00943887047f);
  q = fmaf(q, wt, 1.00167406f);
  q = fmaf(q, wt, 2.83297682f);
  return ((w < 5.0f) ? p : q) * x;
}

#define PE 0.60000002384185791f   // (float)(1.0 - 0.4)

// ---------------- prep: detect + zero counts/stats + Wt transpose ----------------
__global__ __launch_bounds__(256) void prep_kernel(
    const int* __restrict__ adj32, int* __restrict__ flag,
    int* __restrict__ counts, float* __restrict__ stats,
    const float* __restrict__ W, unsigned short* __restrict__ Wt) {
  int idx = blockIdx.x * 256 + threadIdx.x;
  if (blockIdx.x == 0 && threadIdx.x < 64) {
    bool hi_zero = (adj32[2 * threadIdx.x + 1] == 0);
    unsigned long long bl = __ballot(hi_zero);
    if (threadIdx.x == 0) *flag = (bl == ~0ull) ? 1 : 0;
  }
  if (idx < N_NODES) counts[idx] = 0;
  if (idx < 256) stats[idx] = 0.0f;
  if (idx < D_IN * D_H) {  // W (f32 [512][128]) -> Wt (bf16 [128][512])
    int k = idx >> 7, n = idx & 127;
    Wt[n * 512 + k] = f2bf(W[idx]);
  }
}

// ---------------- fused: gen_x with sparsity compaction (4/5) + edge-hist (1/5) ----
// Direct block mapping (r3 version: VGPR 12, ~79% occupancy, 212 us).
#define MAIN_BLKS 31250

__global__ __launch_bounds__(256) void fused_kernel(
    const float* __restrict__ data, unsigned short* __restrict__ x,
    const int* __restrict__ adj32, const int* __restrict__ flag,
    int* __restrict__ counts,
    uint32_t kn0, uint32_t kn1, uint32_t kd10, uint32_t kd11,
    uint32_t kd20, uint32_t kd21, uint32_t ke0, uint32_t ke1) {
  __shared__ uint2 queue[4][512];            // 16 KiB: {d_bits, local_idx}
  __shared__ unsigned short res[4][512];     //  4 KiB: bf16 results
  int b = blockIdx.x;
  if ((b % 5) == 4) {
    // ---- edge-hist block ----
    uint32_t e = (uint32_t)(b / 5) * 256u + threadIdx.x;  // < 1.6M exactly
    int fl = *flag;
    int r = fl ? adj32[2 * e] : adj32[e];
    uint32_t eb = tf_bits(ke0, ke1, e);
    if (bits_to_unit(eb) < PE) atomicAdd(&counts[r], 1);
    return;
  }
  // ---- gen block: 2048 elements; each wave owns a 512-element chunk ----
  uint32_t gblk = (uint32_t)(b / 5) * 4u + (uint32_t)(b % 5);
  const int wave = threadIdx.x >> 6, lane = threadIdx.x & 63;
  const uint32_t wbase = gblk * 2048u + (uint32_t)wave * 512u;
  const uint32_t i0 = wbase + (uint32_t)lane * 8u;
  float4 d0 = *(const float4*)(data + i0);
  float4 d1 = *(const float4*)(data + i0 + 4);
  float dv[8] = {d0.x, d0.y, d0.z, d0.w, d1.x, d1.y, d1.z, d1.w};
  // zero result tile (survivors overwrite in phase 2); dropped -> bf16 +0
  *(uint4*)(&res[wave][lane * 8]) = make_uint4(0u, 0u, 0u, 0u);

  // phase 1: mask-1 threefry for all elements; push survivors (~50%)
  uint32_t qc = 0;
#pragma unroll
  for (int j = 0; j < 8; ++j) {
    uint32_t ab = tf_bits(kd10, kd11, i0 + (uint32_t)j);
    bool keep = (ab >> 31) == 0u;
    unsigned long long m = __ballot(keep);
    uint32_t below = __builtin_amdgcn_mbcnt_hi(
        (uint32_t)(m >> 32), __builtin_amdgcn_mbcnt_lo((uint32_t)m, 0u));
    if (keep)
      queue[wave][qc + below] =
          make_uint2(__float_as_uint(dv[j]), (uint32_t)(lane * 8 + j));
    qc += (uint32_t)__popcll(m);
  }

  // phase 1b: mask-2 threefry on queued entries; compact in place (~25% remain).
  uint32_t qc2 = 0;
  for (uint32_t k0 = 0; k0 < qc; k0 += 64) {
    uint32_t k = k0 + (uint32_t)lane;
    bool act = k < qc;
    uint2 ent = make_uint2(0u, 0u);
    if (act) ent = queue[wave][k];
    uint32_t bb = tf_bits(kd20, kd21, wbase + ent.y);
    bool keep = act && ((bb >> 31) == 0u);
    unsigned long long m = __ballot(keep);
    uint32_t below = __builtin_amdgcn_mbcnt_hi(
        (uint32_t)(m >> 32), __builtin_amdgcn_mbcnt_lo((uint32_t)m, 0u));
    if (keep) queue[wave][qc2 + below] = ent;
    qc2 += (uint32_t)__popcll(m);
  }

  // phase 2: noise threefry + erfinv only for final survivors
  for (uint32_t k0 = 0; k0 < qc2; k0 += 64) {
    uint32_t k = k0 + (uint32_t)lane;
    bool act = k < qc2;
    uint2 ent = make_uint2(0u, 0u);
    if (act) ent = queue[wave][k];
    uint32_t nb = tf_bits(kn0, kn1, wbase + ent.y);
    float f = bits_to_unit(nb);
    float u = fmaf(f, 2.0f, -0.99999994f);  // >= -0.99999994 always
    float z = erfinv_fast(u);
    float val = fmaf(0.0141421356237f, z, __uint_as_float(ent.x));
    unsigned short r = f2bf(val * 4.0f);
    if (act) res[wave][ent.y] = r;
  }

  // phase 3: coalesced 16 B store per lane
  uint4 rr = *(const uint4*)(&res[wave][lane * 8]);
  *(uint4*)(x + i0) = rr;
}

// ---------------- gemm: h = x @ W (bf16 MFMA, f32 acc, fp16 h out) ----------------
typedef __attribute__((ext_vector_type(8))) short bf16x8;
typedef __attribute__((ext_vector_type(4))) float f32x4;
typedef _Float16 half8 __attribute__((ext_vector_type(8)));
#define BM 64
#define BK 64
#define LDT 72  // padded LDS leading dim (elements)

__global__ __launch_bounds__(256) void gemm_kernel(
    const unsigned short* __restrict__ x, const unsigned short* __restrict__ Wt,
    unsigned short* __restrict__ hh) {
  __shared__ __align__(16) unsigned short a_lds[BM * LDT];
  __shared__ __align__(16) unsigned short b_lds[128 * LDT];
  const int tid = threadIdx.x;
  const int r0 = blockIdx.x * BM;
  const int wave = tid >> 6, lane = tid & 63;
  const int lane15 = lane & 15, quad = lane >> 4;
  const int waveM = (wave & 1) * 32, waveN = (wave >> 1) * 64;
  f32x4 acc[2][4] = {};
  for (int kc = 0; kc < D_IN; kc += BK) {
    __syncthreads();
    {
      int row = tid >> 2, q = tid & 3;
      int gr = r0 + row;
      uint4 v0 = make_uint4(0, 0, 0, 0), v1 = v0;
      if (gr < N_NODES) {
        const unsigned short* src = x + (size_t)gr * D_IN + kc + q * 16;
        v0 = *(const uint4*)(src);
        v1 = *(const uint4*)(src + 8);
      }
      *(uint4*)(a_lds + row * LDT + q * 16) = v0;
      *(uint4*)(a_lds + row * LDT + q * 16 + 8) = v1;
    }
    {
      int n = tid >> 1, half = tid & 1;
      const uint4* src = (const uint4*)(Wt + n * 512 + kc + half * 32);
      uint4* dst = (uint4*)(b_lds + n * LDT + half * 32);
      dst[0] = src[0]; dst[1] = src[1]; dst[2] = src[2]; dst[3] = src[3];
    }
    __syncthreads();
    for (int ks = 0; ks < BK; ks += 32) {
      bf16x8 afrag[2], bfrag[4];
      for (int m = 0; m < 2; ++m)
        afrag[m] = *(const bf16x8*)(a_lds + (waveM + m * 16 + lane15) * LDT + ks + quad * 8);
      for (int n = 0; n < 4; ++n)
        bfrag[n] = *(const bf16x8*)(b_lds + (waveN + n * 16 + lane15) * LDT + ks + quad * 8);
      for (int m = 0; m < 2; ++m)
        for (int n = 0; n < 4; ++n)
          acc[m][n] = __builtin_amdgcn_mfma_f32_16x16x32_bf16(afrag[m], bfrag[n], acc[m][n], 0, 0, 0);
    }
  }
  for (int m = 0; m < 2; ++m) {
    int growb = r0 + waveM + m * 16 + quad * 4;
    for (int r = 0; r < 4; ++r) {
      int grow = growb + r;
      if (grow < N_NODES)
        for (int n = 0; n < 4; ++n) {
          _Float16 hv = (_Float16)acc[m][n][r];
          hh[(size_t)grow * D_H + waveN + n * 16 + lane15] =
              __builtin_bit_cast(unsigned short, hv);
        }
    }
  }
}

// ---------------- prefix scan (2 kernels; scan2+3 merged) ----------------
#define SCAN_B 512
#define SCAN_NBLK ((N_NODES + SCAN_B - 1) / SCAN_B)  // 196

__global__ __launch_bounds__(256) void scan1_kernel(const int* __restrict__ counts,
                                                    int* __restrict__ rowstart,
                                                    int* __restrict__ bsums) {
  __shared__ int bufA[SCAN_B], bufB[SCAN_B];
  int t = threadIdx.x, b = blockIdx.x;
  int g0 = b * SCAN_B + t, g1 = g0 + 256;
  int v0 = (g0 < N_NODES) ? counts[g0] : 0;
  int v1 = (g1 < N_NODES) ? counts[g1] : 0;
  bufA[t] = v0; bufA[t + 256] = v1;
  __syncthreads();
  int* src = bufA; int* dst = bufB;
  for (int off = 1; off < SCAN_B; off <<= 1) {
    for (int k = t; k < SCAN_B; k += 256)
      dst[k] = src[k] + ((k >= off) ? src[k - off] : 0);
    __syncthreads();
    int* tmp = src; src = dst; dst = tmp;
  }
  if (g0 < N_NODES) rowstart[g0] = src[t] - v0;
  if (g1 < N_NODES) rowstart[g1] = src[t + 256] - v1;
  if (t == 0) bsums[b] = src[SCAN_B - 1];
}

// each block redundantly scans the 196 block sums (trivial), then applies.
__global__ __launch_bounds__(256) void scan23_kernel(int* __restrict__ rowstart,
                                                     const int* __restrict__ bsums,
                                                     int* __restrict__ cursor) {
  __shared__ int bufA[256], bufB[256];
  __shared__ int bscan_l[256];
  int t = threadIdx.x;
  int v = (t < SCAN_NBLK) ? bsums[t] : 0;
  bufA[t] = v;
  __syncthreads();
  int* src = bufA; int* dst = bufB;
  for (int off = 1; off < 256; off <<= 1) {
    dst[t] = src[t] + ((t >= off) ? src[t - off] : 0);
    __syncthreads();
    int* tmp = src; src = dst; dst = tmp;
  }
  bscan_l[t] = src[t] - v;  // exclusive
  __syncthreads();
  int i = blockIdx.x * 256 + t;
  if (i < N_NODES) {
    int val = rowstart[i] + bscan_l[i / SCAN_B];
    rowstart[i] = val;
    cursor[i] = val;
  }
}

// ---------------- scatter kept edges into CSR (recomputes dropout) ----------------
__global__ __launch_bounds__(256) void scatter_kernel(
    const int* __restrict__ adj32, const int* __restrict__ flag,
    const float* __restrict__ vals, int* __restrict__ cursor,
    int* __restrict__ scol, float* __restrict__ sval,
    uint32_t ke0, uint32_t ke1) {
  uint32_t e = blockIdx.x * 256u + threadIdx.x;
  if (e >= (uint32_t)N_EDGES) return;
  uint32_t eb = tf_bits(ke0, ke1, e);
  if (bits_to_unit(eb) >= PE) return;
  int fl = *flag;
  int r = fl ? adj32[2 * e] : adj32[e];
  int c = fl ? adj32[2 * (N_EDGES + e)] : adj32[N_EDGES + e];
  int pos = atomicAdd(&cursor[r], 1);
  scol[pos] = c;
  sval[pos] = vals[e] / PE;
}

// ---------------- CSR SpMM + ELU + BN-stats: 16-lane group per row ------------
// One group owns one row (no cross-group reduce in hot loop); 4-deep edge
// unroll -> 4 independent 16 B gathers per lane in flight (latency/MLP-bound
// regime per r5 evidence: VALU 8%, HBM 7%). Masked tail slots reuse the last
// edge's column (duplicate cacheline -> free).
__global__ __launch_bounds__(256) void spmm_stats_kernel(
    const int* __restrict__ scol, const float* __restrict__ sval,
    const int* __restrict__ rowstart, const int* __restrict__ counts,
    const unsigned short* __restrict__ hh, float* __restrict__ agg,
    float* __restrict__ stats) {
  __shared__ float ls[4][128], lq[4][128];
  const int t = threadIdx.x;
  const int wave = t >> 6, lane = t & 63;
  const int g = lane >> 4, l4 = lane & 15;
  const unsigned short* hp = hh + l4 * 8;
  const int r = blockIdx.x * 16 + wave * 4 + g;  // 6250*16 == 100000 exactly
  float es[8] = {}, eq[8] = {};
  {
    int start = rowstart[r], len = counts[r];
    float acc[8] = {};
    for (int j = 0; j < len; j += 4) {
      int cc[4]; float vv[4];
#pragma unroll
      for (int u = 0; u < 4; ++u) {
        int jj = j + u;
        int e = start + (jj < len ? jj : len - 1);
        cc[u] = scol[e];
        vv[u] = (jj < len) ? sval[e] : 0.0f;
      }
      uint4 bb[4];
#pragma unroll
      for (int u = 0; u < 4; ++u)
        bb[u] = *(const uint4*)(hp + (size_t)cc[u] * D_H);
#pragma unroll
      for (int u = 0; u < 4; ++u) {
        half8 xv = __builtin_bit_cast(half8, bb[u]);
#pragma unroll
        for (int k = 0; k < 8; ++k) acc[k] = fmaf(vv[u], (float)xv[k], acc[k]);
      }
    }
    // ELU + per-lane stats + store (each group writes its own full row)
    float e8[8];
#pragma unroll
    for (int k = 0; k < 8; ++k) {
      float a = acc[k];
      float e = a > 0.f ? a : expm1f(a);
      e8[k] = e;
      es[k] += e;
      eq[k] += e * e;
    }
    float* op = agg + (size_t)r * D_H + l4 * 8;
    *(float4*)op = make_float4(e8[0], e8[1], e8[2], e8[3]);
    *(float4*)(op + 4) = make_float4(e8[4], e8[5], e8[6], e8[7]);
  }
  // epilogue: cross-group reduce (features align across groups), then block
#pragma unroll
  for (int k = 0; k < 8; ++k) {
    es[k] += __shfl_xor(es[k], 16, 64);
    es[k] += __shfl_xor(es[k], 32, 64);
    eq[k] += __shfl_xor(eq[k], 16, 64);
    eq[k] += __shfl_xor(eq[k], 32, 64);
  }
  if (g == 0) {
#pragma unroll
    for (int k = 0; k < 8; ++k) {
      ls[wave][l4 * 8 + k] = es[k];
      lq[wave][l4 * 8 + k] = eq[k];
    }
  }
  __syncthreads();
  if (t < 128) {
    float s = ls[0][t] + ls[1][t] + ls[2][t] + ls[3][t];
    float q = lq[0][t] + lq[1][t] + lq[2][t] + lq[3][t];
    atomicAdd(&stats[t], s);
    atomicAdd(&stats[128 + t], q);
  }
}

// ---------------- BN apply (agg already holds ELU output; grid-stride) ----------
__global__ __launch_bounds__(256) void bn_kernel(const float* __restrict__ agg,
                                                 const float* __restrict__ stats,
                                                 const float* __restrict__ gamma,
                                                 const float* __restrict__ beta,
                                                 float* __restrict__ out) {
  const float inv_n = 1.0f / (float)N_NODES;
  const int tot4 = N_NODES * D_H / 4;  // 3,200,000
  int idx0 = blockIdx.x * 256 + threadIdx.x;
  int stride = gridDim.x * 256;  // multiple of 32 -> f0 invariant
  int f0 = (idx0 * 4) & 127;
  // hoist per-feature constants (f invariant across iterations)
  float sc[4], sh[4];
#pragma unroll
  for (int j = 0; j < 4; ++j) {
    int f = f0 + j;
    float mean = stats[f] * inv_n;
    float var = stats[128 + f] * inv_n - mean * mean;
    float gsc = gamma[f] * rsqrtf(var + 1e-5f);
    sc[j] = gsc;
    sh[j] = beta[f] - mean * gsc;
  }
  for (int idx4 = idx0; idx4 < tot4; idx4 += stride) {
    size_t base = (size_t)idx4 * 4;
    float4 a = *(const float4*)(agg + base);
    float4 o;
    o.x = fmaf(a.x, sc[0], sh[0]);
    o.y = fmaf(a.y, sc[1], sh[1]);
    o.z = fmaf(a.z, sc[2], sh[2]);
    o.w = fmaf(a.w, sc[3], sh[3]);
    *(float4*)(out + base) = o;
  }
}

// ---------------- launcher ----------------
extern "C" void kernel_launch(void* const* d_in, const int* in_sizes, int n_in,
                              void* d_out, int out_size, void* d_ws, size_t ws_size,
                              hipStream_t stream) {
  const float* data = (const float*)d_in[0];
  const int* adj = (const int*)d_in[1];
  const float* vals = (const float*)d_in[2];
  const float* W = (const float*)d_in[3];
  const float* gamma = (const float*)d_in[4];
  const float* beta = (const float*)d_in[5];
  float* out = (float*)d_out;

  // workspace layout:
  //   [0, 102.4M)      x (bf16)            -- dead after gemm
  //   alias zone (written only after gemm):
  //     [0, 51.2M)     agg
  //     [51.2M, 57.6M) scol
  //     [57.6M, 64.0M) sval
  //     [64.0M, 64.4M) rowstart
  //     [64.4M, 64.8M) cursor
  //     [64.8M, ...)   bsums
  //   [102.4M, 128.0M) h (fp16)
  //   153,600,000      Wt (128K)
  //   153,731,072      stats (1K)
  //   153,732,096      flag (4B)
  //   153,733,120      counts (400K)       -- outside x: live during fused
  char* ws = (char*)d_ws;
  unsigned short* x = (unsigned short*)ws;
  float* agg = (float*)ws;
  int* scol = (int*)(ws + 51200000);
  float* sval = (float*)(ws + 57600000);
  int* rowstart = (int*)(ws + 64000000);
  int* cursor = (int*)(ws + 64400000);
  int* bsums = (int*)(ws + 64800000);
  unsigned short* hh = (unsigned short*)(ws + 102400000);
  unsigned short* Wt = (unsigned short*)(ws + 153600000);
  float* stats = (float*)(ws + 153731072);
  int* flag = (int*)(ws + 153732096);
  int* counts = (int*)(ws + 153733120);

  // host-side: split(key(42), 4) foldlike -> key_i = both words of tf(key,(0,i))
  uint32_t kk[4][2];
  for (uint32_t i = 0; i < 4; ++i) threefry2x32(0u, 42u, 0u, i, kk[i][0], kk[i][1]);
  uint32_t kn0 = kk[0][0], kn1 = kk[0][1];
  uint32_t kd10 = kk[1][0], kd11 = kk[1][1];
  uint32_t kd20 = kk[2][0], kd21 = kk[2][1];
  uint32_t ke0 = kk[3][0], ke1 = kk[3][1];

  prep_kernel<<<391, 256, 0, stream>>>(adj, flag, counts, stats, W, Wt);
  fused_kernel<<<MAIN_BLKS, 256, 0, stream>>>(
      data, x, adj, flag, counts,
      kn0, kn1, kd10, kd11, kd20, kd21, ke0, ke1);
  gemm_kernel<<<(N_NODES + BM - 1) / BM, 256, 0, stream>>>(x, Wt, hh);
  // ---- x dead below; alias zone live ----
  scan1_kernel<<<SCAN_NBLK, 256, 0, stream>>>(counts, rowstart, bsums);
  scan23_kernel<<<391, 256, 0, stream>>>(rowstart, bsums, cursor);
  scatter_kernel<<<6250, 256, 0, stream>>>(adj, flag, vals, cursor, scol, sval, ke0, ke1);
  spmm_stats_kernel<<<6250, 256, 0, stream>>>(scol, sval, rowstart, counts, hh, agg, stats);
  bn_kernel<<<2048, 256, 0, stream>>>(agg, stats, gamma, beta, out);
}

// Round 7
// 559.409 us; speedup vs baseline: 1.9298x; 1.2514x over previous
//
#include <hip/hip_runtime.h>
#include <stdint.h>

#define N_NODES 100000
#define D_IN 512
#define D_H 128
#define N_EDGES 1600000
#define ECAP 48   // ELL capacity; P(kept-degree >= 48) ~ 1e-10 for Poisson(9.6)

// ---------------- threefry2x32 (JAX-compatible, 20 rounds) ----------------
__host__ __device__ __forceinline__ void threefry2x32(uint32_t k0, uint32_t k1,
                                                      uint32_t x0, uint32_t x1,
                                                      uint32_t& o0, uint32_t& o1) {
  uint32_t k2 = k0 ^ k1 ^ 0x1BD11BDAu;
  x0 += k0; x1 += k1;
#if defined(__HIP_DEVICE_COMPILE__)
#define ROTL(v, r) __builtin_rotateleft32((v), (r))
#else
#define ROTL(v, r) (((v) << (r)) | ((v) >> (32 - (r))))
#endif
#define TFR(r) x0 += x1; x1 = ROTL(x1, r); x1 ^= x0;
  TFR(13) TFR(15) TFR(26) TFR(6)
  x0 += k1; x1 += k2 + 1u;
  TFR(17) TFR(29) TFR(16) TFR(24)
  x0 += k2; x1 += k0 + 2u;
  TFR(13) TFR(15) TFR(26) TFR(6)
  x0 += k0; x1 += k1 + 3u;
  TFR(17) TFR(29) TFR(16) TFR(24)
  x0 += k1; x1 += k2 + 4u;
  TFR(13) TFR(15) TFR(26) TFR(6)
  x0 += k2; x1 += k0 + 5u;
#undef TFR
#undef ROTL
  o0 = x0; o1 = x1;
}

// partitionable random_bits for index i (< 2^32): xor of the two output lanes
__device__ __forceinline__ uint32_t tf_bits(uint32_t k0, uint32_t k1, uint32_t i) {
  uint32_t w0, w1;
  threefry2x32(k0, k1, 0u, i, w0, w1);
  return w0 ^ w1;
}

__device__ __forceinline__ float bits_to_unit(uint32_t b) {
  return __uint_as_float((b >> 9) | 0x3f800000u) - 1.0f;
}

__device__ __forceinline__ unsigned short f2bf(float f) {  // RNE, finite only
  uint32_t b = __float_as_uint(f);
  return (unsigned short)((b + 0x7FFFu + ((b >> 16) & 1u)) >> 16);
}

// Giles (2012) single-precision erfinv: ~1e-6 rel err, branch-free select.
__device__ __forceinline__ float erfinv_fast(float x) {
  float w = -__logf(fmaf(-x, x, 1.0f));
  float wc = w - 2.5f;
  float p = 2.81022636e-08f;
  p = fmaf(p, wc, 3.43273939e-07f);
  p = fmaf(p, wc, -3.5233877e-06f);
  p = fmaf(p, wc, -4.39150654e-06f);
  p = fmaf(p, wc, 0.00021858087f);
  p = fmaf(p, wc, -0.00125372503f);
  p = fmaf(p, wc, -0.00417768164f);
  p = fmaf(p, wc, 0.246640727f);
  p = fmaf(p, wc, 1.50140941f);
  // sqrt(w) = w * rsqrt(w); w==0 -> NaN but then w<5 selects p-branch.
  float wt = fmaf(w, rsqrtf(w), -3.0f);
  float q = -0.000200214257f;
  q = fmaf(q, wt, 0.000100950558f);
  q = fmaf(q, wt, 0.00134934322f);
  q = fmaf(q, wt, -0.00367342844f);
  q = fmaf(q, wt, 0.00573950773f);
  q = fmaf(q, wt, -0.0076224613f);
  q = fmaf(q, wt, 0.00943887047f);
  q = fmaf(q, wt, 1.00167406f);
  q = fmaf(q, wt, 2.83297682f);
  return ((w < 5.0f) ? p : q) * x;
}

#define PE 0.60000002384185791f   // (float)(1.0 - 0.4)

// ---------------- prep: detect + zero counts/stats + Wt transpose ----------------
__global__ __launch_bounds__(256) void prep_kernel(
    const int* __restrict__ adj32, int* __restrict__ flag,
    int* __restrict__ counts, float* __restrict__ stats,
    const float* __restrict__ W, unsigned short* __restrict__ Wt) {
  int idx = blockIdx.x * 256 + threadIdx.x;
  if (blockIdx.x == 0 && threadIdx.x < 64) {
    bool hi_zero = (adj32[2 * threadIdx.x + 1] == 0);
    unsigned long long bl = __ballot(hi_zero);
    if (threadIdx.x == 0) *flag = (bl == ~0ull) ? 1 : 0;
  }
  if (idx < N_NODES) counts[idx] = 0;
  if (idx < 256) stats[idx] = 0.0f;
  if (idx < D_IN * D_H) {  // W (f32 [512][128]) -> Wt (bf16 [128][512])
    int k = idx >> 7, n = idx & 127;
    Wt[n * 512 + k] = f2bf(W[idx]);
  }
}

// ---------------- fused: gen_x compaction (4/5) + edge ELL scatter (1/5) --------
// Edge blocks build the padded ELL adjacency directly: the histogram atomicAdd's
// return value IS the slot. No scan, no separate scatter pass, one threefry per
// edge total. Latency of the random ELL writes hides under gen blocks' VALU wall.
#define MAIN_BLKS 31250

__global__ __launch_bounds__(256) void fused_kernel(
    const float* __restrict__ data, unsigned short* __restrict__ x,
    const int* __restrict__ adj32, const int* __restrict__ flag,
    int* __restrict__ counts, const float* __restrict__ vals,
    int* __restrict__ ecol, unsigned short* __restrict__ eval16,
    uint32_t kn0, uint32_t kn1, uint32_t kd10, uint32_t kd11,
    uint32_t kd20, uint32_t kd21, uint32_t ke0, uint32_t ke1) {
  __shared__ uint2 queue[4][512];            // 16 KiB: {d_bits, local_idx}
  __shared__ unsigned short res[4][512];     //  4 KiB: bf16 results
  int b = blockIdx.x;
  if ((b % 5) == 4) {
    // ---- edge block: dropout + direct ELL scatter ----
    uint32_t e = (uint32_t)(b / 5) * 256u + threadIdx.x;  // < 1.6M exactly
    int fl = *flag;
    int r = fl ? adj32[2 * e] : adj32[e];
    uint32_t eb = tf_bits(ke0, ke1, e);
    if (bits_to_unit(eb) < PE) {
      int c = fl ? adj32[2 * (N_EDGES + e)] : adj32[N_EDGES + e];
      float v = vals[e] / PE;
      int slot = atomicAdd(&counts[r], 1);
      if (slot < ECAP) {
        int p = r * ECAP + slot;
        ecol[p] = c;
        _Float16 hv = (_Float16)v;
        eval16[p] = __builtin_bit_cast(unsigned short, hv);
      }
    }
    return;
  }
  // ---- gen block: 2048 elements; each wave owns a 512-element chunk ----
  uint32_t gblk = (uint32_t)(b / 5) * 4u + (uint32_t)(b % 5);
  const int wave = threadIdx.x >> 6, lane = threadIdx.x & 63;
  const uint32_t wbase = gblk * 2048u + (uint32_t)wave * 512u;
  const uint32_t i0 = wbase + (uint32_t)lane * 8u;
  float4 d0 = *(const float4*)(data + i0);
  float4 d1 = *(const float4*)(data + i0 + 4);
  float dv[8] = {d0.x, d0.y, d0.z, d0.w, d1.x, d1.y, d1.z, d1.w};
  // zero result tile (survivors overwrite in phase 2); dropped -> bf16 +0
  *(uint4*)(&res[wave][lane * 8]) = make_uint4(0u, 0u, 0u, 0u);

  // phase 1: mask-1 threefry for all elements; push survivors (~50%)
  uint32_t qc = 0;
#pragma unroll
  for (int j = 0; j < 8; ++j) {
    uint32_t ab = tf_bits(kd10, kd11, i0 + (uint32_t)j);
    bool keep = (ab >> 31) == 0u;
    unsigned long long m = __ballot(keep);
    uint32_t below = __builtin_amdgcn_mbcnt_hi(
        (uint32_t)(m >> 32), __builtin_amdgcn_mbcnt_lo((uint32_t)m, 0u));
    if (keep)
      queue[wave][qc + below] =
          make_uint2(__float_as_uint(dv[j]), (uint32_t)(lane * 8 + j));
    qc += (uint32_t)__popcll(m);
  }

  // phase 1b: mask-2 threefry on queued entries; compact in place (~25% remain).
  uint32_t qc2 = 0;
  for (uint32_t k0 = 0; k0 < qc; k0 += 64) {
    uint32_t k = k0 + (uint32_t)lane;
    bool act = k < qc;
    uint2 ent = make_uint2(0u, 0u);
    if (act) ent = queue[wave][k];
    uint32_t bb = tf_bits(kd20, kd21, wbase + ent.y);
    bool keep = act && ((bb >> 31) == 0u);
    unsigned long long m = __ballot(keep);
    uint32_t below = __builtin_amdgcn_mbcnt_hi(
        (uint32_t)(m >> 32), __builtin_amdgcn_mbcnt_lo((uint32_t)m, 0u));
    if (keep) queue[wave][qc2 + below] = ent;
    qc2 += (uint32_t)__popcll(m);
  }

  // phase 2: noise threefry + erfinv only for final survivors
  for (uint32_t k0 = 0; k0 < qc2; k0 += 64) {
    uint32_t k = k0 + (uint32_t)lane;
    bool act = k < qc2;
    uint2 ent = make_uint2(0u, 0u);
    if (act) ent = queue[wave][k];
    uint32_t nb = tf_bits(kn0, kn1, wbase + ent.y);
    float f = bits_to_unit(nb);
    float u = fmaf(f, 2.0f, -0.99999994f);  // >= -0.99999994 always
    float z = erfinv_fast(u);
    float val = fmaf(0.0141421356237f, z, __uint_as_float(ent.x));
    unsigned short r = f2bf(val * 4.0f);
    if (act) res[wave][ent.y] = r;
  }

  // phase 3: coalesced 16 B store per lane
  uint4 rr = *(const uint4*)(&res[wave][lane * 8]);
  *(uint4*)(x + i0) = rr;
}

// ---------------- gemm: h = x @ W (bf16 MFMA, f32 acc, fp16 h out) ----------------
typedef __attribute__((ext_vector_type(8))) short bf16x8;
typedef __attribute__((ext_vector_type(4))) float f32x4;
typedef _Float16 half8 __attribute__((ext_vector_type(8)));
#define BM 64
#define BK 64
#define LDT 72  // padded LDS leading dim (elements)

__global__ __launch_bounds__(256) void gemm_kernel(
    const unsigned short* __restrict__ x, const unsigned short* __restrict__ Wt,
    unsigned short* __restrict__ hh) {
  __shared__ __align__(16) unsigned short a_lds[BM * LDT];
  __shared__ __align__(16) unsigned short b_lds[128 * LDT];
  const int tid = threadIdx.x;
  const int r0 = blockIdx.x * BM;
  const int wave = tid >> 6, lane = tid & 63;
  const int lane15 = lane & 15, quad = lane >> 4;
  const int waveM = (wave & 1) * 32, waveN = (wave >> 1) * 64;
  f32x4 acc[2][4] = {};
  for (int kc = 0; kc < D_IN; kc += BK) {
    __syncthreads();
    {
      int row = tid >> 2, q = tid & 3;
      int gr = r0 + row;
      uint4 v0 = make_uint4(0, 0, 0, 0), v1 = v0;
      if (gr < N_NODES) {
        const unsigned short* src = x + (size_t)gr * D_IN + kc + q * 16;
        v0 = *(const uint4*)(src);
        v1 = *(const uint4*)(src + 8);
      }
      *(uint4*)(a_lds + row * LDT + q * 16) = v0;
      *(uint4*)(a_lds + row * LDT + q * 16 + 8) = v1;
    }
    {
      int n = tid >> 1, half = tid & 1;
      const uint4* src = (const uint4*)(Wt + n * 512 + kc + half * 32);
      uint4* dst = (uint4*)(b_lds + n * LDT + half * 32);
      dst[0] = src[0]; dst[1] = src[1]; dst[2] = src[2]; dst[3] = src[3];
    }
    __syncthreads();
    for (int ks = 0; ks < BK; ks += 32) {
      bf16x8 afrag[2], bfrag[4];
      for (int m = 0; m < 2; ++m)
        afrag[m] = *(const bf16x8*)(a_lds + (waveM + m * 16 + lane15) * LDT + ks + quad * 8);
      for (int n = 0; n < 4; ++n)
        bfrag[n] = *(const bf16x8*)(b_lds + (waveN + n * 16 + lane15) * LDT + ks + quad * 8);
      for (int m = 0; m < 2; ++m)
        for (int n = 0; n < 4; ++n)
          acc[m][n] = __builtin_amdgcn_mfma_f32_16x16x32_bf16(afrag[m], bfrag[n], acc[m][n], 0, 0, 0);
    }
  }
  for (int m = 0; m < 2; ++m) {
    int growb = r0 + waveM + m * 16 + quad * 4;
    for (int r = 0; r < 4; ++r) {
      int grow = growb + r;
      if (grow < N_NODES)
        for (int n = 0; n < 4; ++n) {
          _Float16 hv = (_Float16)acc[m][n][r];
          hh[(size_t)grow * D_H + waveN + n * 16 + lane15] =
              __builtin_bit_cast(unsigned short, hv);
        }
    }
  }
}

// ---------------- ELL SpMM + ELU + BN-stats (r4 structure, grid-stride) --------
// Wave per row; 4 edges concurrently via 16-lane groups; 2-deep unroll -> 8
// independent 16 B gathers in flight. start = r*ECAP (no rowstart array).
__global__ __launch_bounds__(256) void spmm_stats_kernel(
    const int* __restrict__ ecol, const unsigned short* __restrict__ eval16,
    const int* __restrict__ counts, const unsigned short* __restrict__ hh,
    float* __restrict__ agg, float* __restrict__ stats) {
  __shared__ float ls[4][128], lq[4][128];
  const int wave = threadIdx.x >> 6, lane = threadIdx.x & 63;
  const int g = lane >> 4, l4 = lane & 15;
  const unsigned short* hp = hh + l4 * 8;
  float es[8] = {}, eq[8] = {};
  const int wstride = gridDim.x * 4;
  for (int r = blockIdx.x * 4 + wave; r < N_NODES; r += wstride) {
    int start = r * ECAP;
    int len = min(counts[r], ECAP);
    float acc[8] = {};
    int j = 0;
    for (; j + 8 <= len; j += 8) {
      int e0 = start + j + g, e1 = e0 + 4;
      int c0 = ecol[e0], c1 = ecol[e1];
      float v0 = (float)__builtin_bit_cast(_Float16, eval16[e0]);
      float v1 = (float)__builtin_bit_cast(_Float16, eval16[e1]);
      uint4 b0 = *(const uint4*)(hp + (size_t)c0 * D_H);
      uint4 b1 = *(const uint4*)(hp + (size_t)c1 * D_H);
      half8 x0 = __builtin_bit_cast(half8, b0);
      half8 x1 = __builtin_bit_cast(half8, b1);
#pragma unroll
      for (int k = 0; k < 8; ++k) {
        acc[k] = fmaf(v0, (float)x0[k], acc[k]);
        acc[k] = fmaf(v1, (float)x1[k], acc[k]);
      }
    }
    if (j + g < len) {
      int e = start + j + g;
      int c = ecol[e];
      float v = (float)__builtin_bit_cast(_Float16, eval16[e]);
      uint4 bb = *(const uint4*)(hp + (size_t)c * D_H);
      half8 xv = __builtin_bit_cast(half8, bb);
#pragma unroll
      for (int k = 0; k < 8; ++k) acc[k] = fmaf(v, (float)xv[k], acc[k]);
    }
    if (j + 4 + g < len) {
      int e = start + j + 4 + g;
      int c = ecol[e];
      float v = (float)__builtin_bit_cast(_Float16, eval16[e]);
      uint4 bb = *(const uint4*)(hp + (size_t)c * D_H);
      half8 xv = __builtin_bit_cast(half8, bb);
#pragma unroll
      for (int k = 0; k < 8; ++k) acc[k] = fmaf(v, (float)xv[k], acc[k]);
    }
    // combine the 4 groups: butterfly over lane bits 4,5
#pragma unroll
    for (int k = 0; k < 8; ++k) {
      acc[k] += __shfl_xor(acc[k], 16, 64);
      acc[k] += __shfl_xor(acc[k], 32, 64);
    }
    if (g == 0) {
      float e8[8];
#pragma unroll
      for (int k = 0; k < 8; ++k) {
        float a = acc[k];
        float e = a > 0.f ? a : expm1f(a);
        e8[k] = e;
        es[k] += e;
        eq[k] += e * e;
      }
      float* op = agg + (size_t)r * D_H + l4 * 8;
      *(float4*)op = make_float4(e8[0], e8[1], e8[2], e8[3]);
      *(float4*)(op + 4) = make_float4(e8[4], e8[5], e8[6], e8[7]);
    }
  }
  // block-level stats reduce: each wave's group 0 holds 128 features
  if (g == 0) {
#pragma unroll
    for (int k = 0; k < 8; ++k) {
      ls[wave][l4 * 8 + k] = es[k];
      lq[wave][l4 * 8 + k] = eq[k];
    }
  }
  __syncthreads();
  if (threadIdx.x < 128) {
    int t = threadIdx.x;
    float s = ls[0][t] + ls[1][t] + ls[2][t] + ls[3][t];
    float q = lq[0][t] + lq[1][t] + lq[2][t] + lq[3][t];
    atomicAdd(&stats[t], s);
    atomicAdd(&stats[128 + t], q);
  }
}

// ---------------- BN apply (agg already holds ELU output; grid-stride) ----------
__global__ __launch_bounds__(256) void bn_kernel(const float* __restrict__ agg,
                                                 const float* __restrict__ stats,
                                                 const float* __restrict__ gamma,
                                                 const float* __restrict__ beta,
                                                 float* __restrict__ out) {
  const float inv_n = 1.0f / (float)N_NODES;
  const int tot4 = N_NODES * D_H / 4;  // 3,200,000
  int idx0 = blockIdx.x * 256 + threadIdx.x;
  int stride = gridDim.x * 256;  // multiple of 32 -> f0 invariant
  int f0 = (idx0 * 4) & 127;
  // hoist per-feature constants (f invariant across iterations)
  float sc[4], sh[4];
#pragma unroll
  for (int j = 0; j < 4; ++j) {
    int f = f0 + j;
    float mean = stats[f] * inv_n;
    float var = stats[128 + f] * inv_n - mean * mean;
    float gsc = gamma[f] * rsqrtf(var + 1e-5f);
    sc[j] = gsc;
    sh[j] = beta[f] - mean * gsc;
  }
  for (int idx4 = idx0; idx4 < tot4; idx4 += stride) {
    size_t base = (size_t)idx4 * 4;
    float4 a = *(const float4*)(agg + base);
    float4 o;
    o.x = fmaf(a.x, sc[0], sh[0]);
    o.y = fmaf(a.y, sc[1], sh[1]);
    o.z = fmaf(a.z, sc[2], sh[2]);
    o.w = fmaf(a.w, sc[3], sh[3]);
    *(float4*)(out + base) = o;
  }
}

// ---------------- launcher ----------------
extern "C" void kernel_launch(void* const* d_in, const int* in_sizes, int n_in,
                              void* d_out, int out_size, void* d_ws, size_t ws_size,
                              hipStream_t stream) {
  const float* data = (const float*)d_in[0];
  const int* adj = (const int*)d_in[1];
  const float* vals = (const float*)d_in[2];
  const float* W = (const float*)d_in[3];
  const float* gamma = (const float*)d_in[4];
  const float* beta = (const float*)d_in[5];
  float* out = (float*)d_out;

  // workspace layout (max offset ~157.3 MB; ws >= 160.1 MB proven round-1):
  //   [0, 102.4M)        x (bf16)          -- dead after gemm
  //     alias: [0,51.2M) agg               -- written only after gemm
  //   [102.4M, 128.0M)   hh (fp16)
  //   [128.0M, 147.2M)   ecol (int32, ELL CAP=48)
  //   [147.2M, 156.8M)   eval16 (fp16, ELL)
  //   156,800,000        Wt (128K)
  //   156,931,072+       stats (1K), flag (4B), counts (400K)
  char* ws = (char*)d_ws;
  unsigned short* x = (unsigned short*)ws;
  float* agg = (float*)ws;
  unsigned short* hh = (unsigned short*)(ws + 102400000);
  int* ecol = (int*)(ws + 128000000);
  unsigned short* eval16 = (unsigned short*)(ws + 147200000);
  unsigned short* Wt = (unsigned short*)(ws + 156800000);
  float* stats = (float*)(ws + 156932096);
  int* flag = (int*)(ws + 156933120);
  int* counts = (int*)(ws + 156934144);

  // host-side: split(key(42), 4) foldlike -> key_i = both words of tf(key,(0,i))
  uint32_t kk[4][2];
  for (uint32_t i = 0; i < 4; ++i) threefry2x32(0u, 42u, 0u, i, kk[i][0], kk[i][1]);
  uint32_t kn0 = kk[0][0], kn1 = kk[0][1];
  uint32_t kd10 = kk[1][0], kd11 = kk[1][1];
  uint32_t kd20 = kk[2][0], kd21 = kk[2][1];
  uint32_t ke0 = kk[3][0], ke1 = kk[3][1];

  prep_kernel<<<391, 256, 0, stream>>>(adj, flag, counts, stats, W, Wt);
  fused_kernel<<<MAIN_BLKS, 256, 0, stream>>>(
      data, x, adj, flag, counts, vals, ecol, eval16,
      kn0, kn1, kd10, kd11, kd20, kd21, ke0, ke1);
  gemm_kernel<<<(N_NODES + BM - 1) / BM, 256, 0, stream>>>(x, Wt, hh);
  // ---- x dead below; agg alias live ----
  spmm_stats_kernel<<<2048, 256, 0, stream>>>(ecol, eval16, counts, hh, agg, stats);
  bn_kernel<<<2048, 256, 0, stream>>>(agg, stats, gamma, beta, out);
}